// Round 7
// baseline (324.759 us; speedup 1.0000x reference)
//
#include <hip/hip_runtime.h>
#include <math.h>

#define M 50
#define SQRT5 2.2360679774997896f

typedef float f32x2 __attribute__((ext_vector_type(2)));
typedef float f32x4 __attribute__((ext_vector_type(4)));

__constant__ float c_zscale[5] = {0.25f, 0.2f, 0.08f, 400.0f, 10.0f};
__constant__ float c_zshift[5] = {0.0f, 0.0f, 0.0f, 800.0f, 12.0f};

#if __has_builtin(__builtin_amdgcn_sqrtf)
__device__ __forceinline__ float fsqrt(float x) { return __builtin_amdgcn_sqrtf(x); }
#else
__device__ __forceinline__ float fsqrt(float x) { return sqrtf(x); }
#endif

#if __has_builtin(__builtin_amdgcn_exp2f)
__device__ __forceinline__ float fexp2(float x) { return __builtin_amdgcn_exp2f(x); }
#else
__device__ __forceinline__ float fexp2(float x) { return exp2f(x); }
#endif

__device__ __forceinline__ float lane_bcast(float v, int lane) {
    return __builtin_bit_cast(float,
        __builtin_amdgcn_readlane(__builtin_bit_cast(int, v), lane));
}

// Packed-pair triangular layout of Ap = pv^2*(A+A^T) upper-tri:
// row m covers n in [n0, 49], n0 = m & ~1. For odd m the lead pair is
// (0, diag). NP(m) = 25 - (m>>1) pairs of real data, padded to even count
// NPP so every row is a whole number of float4 (2-pair) chunks.
__host__ __device__ constexpr int NPf(int m) { return 25 - (m >> 1); }
__host__ __device__ constexpr int NPP(int m) { return NPf(m) + (NPf(m) & 1); }
__host__ __device__ constexpr int PO(int m) {
    int s = 0;
    for (int i = 0; i < m; ++i) s += NPP(i);
    return s;
}
#define PP_TOT 676   /* == PO(50); 1352 floats */

// ---------------------------------------------------------------------------
// ws layout (floats):
//   [0    .. 1352)  P: packed pairs (float2 flattened), zero-padded
//   [1352 .. 1602)  Zb[m][j] = -2*sqrt5*Zs[m][j]
//   [1602 .. 1652)  z2s[m]   = |sqrt5*Zs[m]|^2 + 5e-8
//   [1652 .. 1657)  ils[j]   = sqrt5 * inv_ls[j]
//   [1657]          prior_var
// ---------------------------------------------------------------------------
// Setup v4: 64 threads (one wave). In-place Gauss-Jordan inversion (identity
// implicit) -> only r[50] per lane (~64 VGPR). __launch_bounds__(64,1) gives
// the allocator a 512-VGPR budget so nothing spills (round-6 pathology:
// VGPR_Count=48 for a 110-float state -> scratch -> 265us).
// ---------------------------------------------------------------------------
__global__ __launch_bounds__(64, 1) void gp_setup(const float* __restrict__ log_ls,
                                                  const float* __restrict__ log_var,
                                                  const float* __restrict__ zraw,
                                                  float* __restrict__ ws) {
    __shared__ float s_ils[5];
    __shared__ float s_pv;
    __shared__ float s_Zs[M * 5];
    __shared__ float s_K[M * M];

    const int t = threadIdx.x;

    if (t == 0) s_pv = expf(log_var[0]);
    if (t < 5)  s_ils[t] = 1.0f / (expf(log_ls[t]) + 1e-8f);
    __syncthreads();
    for (int e = t; e < M * 5; e += 64) {
        int j = e % 5;
        s_Zs[e] = (tanhf(zraw[e]) * c_zscale[j] + c_zshift[j]) * s_ils[j];
    }
    __syncthreads();
    const float pv = s_pv;

    // K + 1e-4 I
    for (int e = t; e < M * M; e += 64) {
        int i = e / M, j = e % M;
        float d2 = 0.0f;
        #pragma unroll
        for (int q = 0; q < 5; ++q) {
            float df = s_Zs[i * 5 + q] - s_Zs[j * 5 + q];
            d2 = fmaf(df, df, d2);
        }
        float d = fsqrt(d2 + 1e-8f);
        float s = SQRT5 * d;
        s_K[e] = pv * (1.0f + s + (5.0f / 3.0f) * (d * d)) * expf(-s)
                 + ((i == j) ? 1e-4f : 0.0f);
    }
    __syncthreads();

    // Single-wave in-place GJ: lane j owns column j (r[50] registers).
    {
        const int j = t;
        const int jc = (j < M) ? j : (M - 1);
        float r[M];
        #pragma unroll
        for (int i = 0; i < M; ++i) r[i] = s_K[i * M + jc];

        #pragma unroll
        for (int p = 0; p < M; ++p) {
            const float piv = lane_bcast(r[p], p);
            const float ip  = 1.0f / piv;
            const bool  onp = (j == p);
            const float rowv = onp ? ip : r[p] * ip;   // A'[p][j]
            #pragma unroll
            for (int i = 0; i < M; ++i) {
                if (i == p) continue;
                const float cp = lane_bcast(r[i], p);  // old A[i][p]
                r[i] = fmaf(-cp, rowv, onp ? 0.0f : r[i]);
            }
            r[p] = rowv;
        }
        if (j < M) {
            #pragma unroll
            for (int i = 0; i < M; ++i) s_K[i * M + j] = r[i];  // s_K := K^-1
        }
    }
    __syncthreads();

    // Zero P, then fill (disjoint writers; barrier orders zero vs fill)
    for (int e = t; e < 2 * PP_TOT; e += 64) ws[e] = 0.0f;
    __syncthreads();

    const float pv2 = pv * pv;
    for (int e = t; e < M * M; e += 64) {
        int m = e / M, n = e % M;
        if (n < m) continue;
        float v = (m == n) ? s_K[m * M + m] : (s_K[m * M + n] + s_K[n * M + m]);
        v *= pv2;
        int n0 = m & ~1;
        int d  = n - n0;
        // pair offset: runtime PO (small loop, setup only)
        int po = 0;
        for (int i = 0; i < m; ++i) { int np = 25 - (i >> 1); po += np + (np & 1); }
        ws[(po + (d >> 1)) * 2 + (d & 1)] = v;
    }

    for (int e = t; e < M * 5; e += 64) ws[1352 + e] = -2.0f * SQRT5 * s_Zs[e];
    for (int e = t; e < M; e += 64) {
        float z2 = 0.0f;
        #pragma unroll
        for (int q = 0; q < 5; ++q) {
            float v = SQRT5 * s_Zs[e * 5 + q];
            z2 = fmaf(v, v, z2);
        }
        ws[1602 + e] = z2 + 5e-8f;
    }
    if (t < 5)  ws[1652 + t] = SQRT5 * s_ils[t];
    if (t == 0) ws[1657] = pv;
}

// ---------------------------------------------------------------------------
// Main kernel. Quad form via v_pk_fma_f32 (2 fp32 FMA/slot) with A-pairs
// streamed from LDS via uniform-address ds_read_b128 (4 values/slot,
// broadcast, conflict-free). Every k use is an asm "v" operand -> must live
// in arch VGPRs (kills the round-3..6 AGPR-parking tax by construction).
// ---------------------------------------------------------------------------
__device__ __forceinline__ void pkfma(f32x2& acc, f32x2 a, f32x2 b) {
    asm("v_pk_fma_f32 %0, %1, %2, %0" : "+v"(acc) : "v"(a), "v"(b));
}

__global__ __launch_bounds__(256, 4) void gp_var(const float* __restrict__ x,
                                                 const float* __restrict__ ws,
                                                 float* __restrict__ out, int B) {
    __shared__ float sx[1280];
    __shared__ float sP[2 * PP_TOT] __attribute__((aligned(16)));
    const int t = threadIdx.x;
    const int gid = blockIdx.x * 256 + t;
    const long long base = (long long)blockIdx.x * 1280;

    {
        // stage A-pairs (338 float4) and this block's inputs (320 float4)
        const float4* wv = (const float4*)ws;
        for (int i = t; i < 2 * PP_TOT / 4; i += 256) ((float4*)sP)[i] = wv[i];
        const long long tot = (long long)B * 5;
        const float4* xv = (const float4*)(x + base);
        for (int i = t; i < 320; i += 256) {
            if (base + (long long)i * 4 + 3 < tot) ((float4*)sx)[i] = xv[i];
        }
    }
    __syncthreads();
    if (gid >= B) return;

    const float* __restrict__ Zb  = ws + 1352;
    const float* __restrict__ z2s = ws + 1602;
    const float* __restrict__ ils = ws + 1652;
    const float pv = ws[1657];

    float xs[5];
    #pragma unroll
    for (int j = 0; j < 5; ++j) xs[j] = sx[t * 5 + j] * ils[j];

    float x2 = 0.0f;
    #pragma unroll
    for (int j = 0; j < 5; ++j) x2 = fmaf(xs[j], xs[j], x2);

    f32x2 kp[25];
    #pragma unroll
    for (int m = 0; m < M; ++m) {
        float u = x2 + z2s[m];
        #pragma unroll
        for (int j = 0; j < 5; ++j) u = fmaf(Zb[m * 5 + j], xs[j], u);
        u = fmaxf(u, 5e-8f);
        float s = fsqrt(u);
        float e = fexp2(s * -1.4426950408889634f);          // exp(-s)
        float kv = fmaf(u, (1.0f / 3.0f), 1.0f + s) * e;
        if (m & 1) kp[m >> 1].y = kv; else kp[m >> 1].x = kv;
    }

    float red = 0.0f;
    #pragma unroll
    for (int m = 0; m < M; ++m) {
        const int h  = m >> 1;
        const int po = PO(m);
        const int nq = NPP(m) / 2;      // float4 chunks this row
        f32x2 acc; acc.x = 0.0f; acc.y = 0.0f;
        #pragma unroll
        for (int q = 0; q < nq; ++q) {
            f32x4 c = *(const f32x4*)&sP[(po + 2 * q) * 2];
            const int k0 = (h + 2 * q < 25)     ? h + 2 * q     : 0;  // pad pair -> A=0
            const int k1 = (h + 2 * q + 1 < 25) ? h + 2 * q + 1 : 0;
            pkfma(acc, c.xy, kp[k0]);
            pkfma(acc, c.zw, kp[k1]);
        }
        float tm = acc.x + acc.y;
        float km = (m & 1) ? kp[h].y : kp[h].x;
        red = fmaf(km, tm, red);
    }

    out[gid] = fsqrt(fmaxf(pv - red, 1e-6f));
}

extern "C" void kernel_launch(void* const* d_in, const int* in_sizes, int n_in,
                              void* d_out, int out_size, void* d_ws, size_t ws_size,
                              hipStream_t stream) {
    const float* x    = (const float*)d_in[0];
    const float* ll   = (const float*)d_in[1];
    const float* lv   = (const float*)d_in[2];
    const float* zraw = (const float*)d_in[3];
    float* out = (float*)d_out;
    float* ws  = (float*)d_ws;

    const int B = in_sizes[0] / 5;

    hipLaunchKernelGGL(gp_setup, dim3(1), dim3(64), 0, stream, ll, lv, zraw, ws);
    const int grid = (B + 255) / 256;
    hipLaunchKernelGGL(gp_var, dim3(grid), dim3(256), 0, stream, x, ws, out, B);
}

// Round 8
// 90.125 us; speedup vs baseline: 3.6034x; 3.6034x over previous
//
#include <hip/hip_runtime.h>
#include <math.h>

#define M 50
#define SQRT5 2.2360679774997896f

typedef float f32x2 __attribute__((ext_vector_type(2)));
typedef float f32x4 __attribute__((ext_vector_type(4)));

__constant__ float c_zscale[5] = {0.25f, 0.2f, 0.08f, 400.0f, 10.0f};
__constant__ float c_zshift[5] = {0.0f, 0.0f, 0.0f, 800.0f, 12.0f};

#if __has_builtin(__builtin_amdgcn_sqrtf)
__device__ __forceinline__ float fsqrt(float x) { return __builtin_amdgcn_sqrtf(x); }
#else
__device__ __forceinline__ float fsqrt(float x) { return sqrtf(x); }
#endif

#if __has_builtin(__builtin_amdgcn_exp2f)
__device__ __forceinline__ float fexp2(float x) { return __builtin_amdgcn_exp2f(x); }
#else
__device__ __forceinline__ float fexp2(float x) { return exp2f(x); }
#endif

__device__ __forceinline__ float lane_bcast(float v, int lane) {
    return __builtin_bit_cast(float,
        __builtin_amdgcn_readlane(__builtin_bit_cast(int, v), lane));
}

// Packed-pair triangular layout of Ap = pv^2*(A+A^T) upper-tri:
// row m covers n in [n0, 49], n0 = m & ~1. For odd m the lead pair is
// (0, diag). NP(m) = 25 - (m>>1) pairs of real data, padded to even count
// NPP so every row is a whole number of float4 (2-pair) chunks.
__host__ __device__ constexpr int NPf(int m) { return 25 - (m >> 1); }
__host__ __device__ constexpr int NPP(int m) { return NPf(m) + (NPf(m) & 1); }
__host__ __device__ constexpr int PO(int m) {
    int s = 0;
    for (int i = 0; i < m; ++i) s += NPP(i);
    return s;
}
#define PP_TOT 676   /* == PO(50); 1352 floats */

// ---- preprocessor 0..49 repeat machinery (GJ must be LITERALLY unrolled:
//      rounds 6/7 showed #pragma unroll silently fails on the pivot loop,
//      making r[p] runtime-indexed -> scratch-lowered -> 265-284us) ----
#define FOR50(F) F(0) F(1) F(2) F(3) F(4) F(5) F(6) F(7) F(8) F(9) \
  F(10) F(11) F(12) F(13) F(14) F(15) F(16) F(17) F(18) F(19) \
  F(20) F(21) F(22) F(23) F(24) F(25) F(26) F(27) F(28) F(29) \
  F(30) F(31) F(32) F(33) F(34) F(35) F(36) F(37) F(38) F(39) \
  F(40) F(41) F(42) F(43) F(44) F(45) F(46) F(47) F(48) F(49)
#define FOR50P(F, p) F(0,p) F(1,p) F(2,p) F(3,p) F(4,p) F(5,p) F(6,p) F(7,p) F(8,p) F(9,p) \
  F(10,p) F(11,p) F(12,p) F(13,p) F(14,p) F(15,p) F(16,p) F(17,p) F(18,p) F(19,p) \
  F(20,p) F(21,p) F(22,p) F(23,p) F(24,p) F(25,p) F(26,p) F(27,p) F(28,p) F(29,p) \
  F(30,p) F(31,p) F(32,p) F(33,p) F(34,p) F(35,p) F(36,p) F(37,p) F(38,p) F(39,p) \
  F(40,p) F(41,p) F(42,p) F(43,p) F(44,p) F(45,p) F(46,p) F(47,p) F(48,p) F(49,p)

#define DECL_R(i) float r##i;
#define INIT_R(i) r##i = s_K[(i) * M + jc];
// in-place GJ column update, lane j owns column j:
//   cp = old a[i][p] (from lane p); rowv = new row-p value at this column;
//   j==p column becomes -cp/piv (the 0 arm), others a[i][j]-cp*rowv.
#define UPD(i, p) if ((i) != (p)) { \
    const float cp = lane_bcast(r##i, (p)); \
    r##i = fmaf(-cp, rowv, onp ? 0.0f : r##i); }
#define PIVOT(p) { \
    const float piv  = lane_bcast(r##p, (p)); \
    const float ipv  = 1.0f / piv; \
    const bool  onp  = (j == (p)); \
    const float rowv = onp ? ipv : r##p * ipv; \
    FOR50P(UPD, p) \
    r##p = rowv; }
#define WB_R(i) s_K[(i) * M + j] = r##i;

// ---------------------------------------------------------------------------
// ws layout (floats):
//   [0    .. 1352)  P: packed pairs (float2 flattened), zero-padded
//   [1352 .. 1602)  Zb[m][j] = -2*sqrt5*Zs[m][j]
//   [1602 .. 1652)  z2s[m]   = |sqrt5*Zs[m]|^2 + 5e-8
//   [1652 .. 1657)  ils[j]   = sqrt5 * inv_ls[j]
//   [1657]          prior_var
// ---------------------------------------------------------------------------
__global__ __launch_bounds__(256, 1) void gp_setup(const float* __restrict__ log_ls,
                                                   const float* __restrict__ log_var,
                                                   const float* __restrict__ zraw,
                                                   float* __restrict__ ws) {
    __shared__ float s_ils[5];
    __shared__ float s_pv;
    __shared__ float s_Zs[M * 5];
    __shared__ float s_K[M * M];

    const int t = threadIdx.x;

    if (t == 0) s_pv = expf(log_var[0]);
    if (t < 5)  s_ils[t] = 1.0f / (expf(log_ls[t]) + 1e-8f);
    __syncthreads();
    if (t < M * 5) {
        int j = t % 5;
        s_Zs[t] = (tanhf(zraw[t]) * c_zscale[j] + c_zshift[j]) * s_ils[j];
    }
    __syncthreads();
    const float pv = s_pv;

    // K + 1e-4 I (parallel across 256 threads)
    for (int e = t; e < M * M; e += 256) {
        int i = e / M, jj = e % M;
        float d2 = 0.0f;
        #pragma unroll
        for (int q = 0; q < 5; ++q) {
            float df = s_Zs[i * 5 + q] - s_Zs[jj * 5 + q];
            d2 = fmaf(df, df, d2);
        }
        float d = fsqrt(d2 + 1e-8f);
        float s = SQRT5 * d;
        s_K[e] = pv * (1.0f + s + (5.0f / 3.0f) * (d * d)) * expf(-s)
                 + ((i == jj) ? 1e-4f : 0.0f);
    }
    __syncthreads();

    // Wave 0: in-place Gauss-Jordan, 50 named scalar registers per lane,
    // fully macro-unrolled (no dynamic indexing anywhere). s_K := K^-1.
    if (t < 64) {
        const int j  = t;
        const int jc = (j < M) ? j : (M - 1);
        FOR50(DECL_R)
        FOR50(INIT_R)
        FOR50(PIVOT)
        if (j < M) { FOR50(WB_R) }
    }
    __syncthreads();

    // Zero P region, then fill (barrier orders zero vs fill)
    for (int e = t; e < 2 * PP_TOT; e += 256) ws[e] = 0.0f;
    __syncthreads();

    const float pv2 = pv * pv;
    for (int e = t; e < M * M; e += 256) {
        int m = e / M, n = e % M;
        if (n < m) continue;
        float v = (m == n) ? s_K[m * M + m] : (s_K[m * M + n] + s_K[n * M + m]);
        v *= pv2;
        int n0 = m & ~1;
        int d  = n - n0;
        int po = 0;
        for (int i = 0; i < m; ++i) { int np = 25 - (i >> 1); po += np + (np & 1); }
        ws[(po + (d >> 1)) * 2 + (d & 1)] = v;
    }

    if (t < M * 5) ws[1352 + t] = -2.0f * SQRT5 * s_Zs[t];
    if (t < M) {
        float z2 = 0.0f;
        #pragma unroll
        for (int q = 0; q < 5; ++q) {
            float v = SQRT5 * s_Zs[t * 5 + q];
            z2 = fmaf(v, v, z2);
        }
        ws[1602 + t] = z2 + 5e-8f;
    }
    if (t < 5)  ws[1652 + t] = SQRT5 * s_ils[t];
    if (t == 0) ws[1657] = pv;
}

// ---------------------------------------------------------------------------
// Main kernel (byte-identical to round 7 for attribution). Quad form via
// v_pk_fma_f32 with A-pairs from LDS (uniform-address float4 broadcast);
// every k use is an asm "v" operand -> arch-VGPR residency by construction.
// ---------------------------------------------------------------------------
__device__ __forceinline__ void pkfma(f32x2& acc, f32x2 a, f32x2 b) {
    asm("v_pk_fma_f32 %0, %1, %2, %0" : "+v"(acc) : "v"(a), "v"(b));
}

__global__ __launch_bounds__(256, 4) void gp_var(const float* __restrict__ x,
                                                 const float* __restrict__ ws,
                                                 float* __restrict__ out, int B) {
    __shared__ float sx[1280];
    __shared__ float sP[2 * PP_TOT] __attribute__((aligned(16)));
    const int t = threadIdx.x;
    const int gid = blockIdx.x * 256 + t;
    const long long base = (long long)blockIdx.x * 1280;

    {
        const float4* wv = (const float4*)ws;
        for (int i = t; i < 2 * PP_TOT / 4; i += 256) ((float4*)sP)[i] = wv[i];
        const long long tot = (long long)B * 5;
        const float4* xv = (const float4*)(x + base);
        for (int i = t; i < 320; i += 256) {
            if (base + (long long)i * 4 + 3 < tot) ((float4*)sx)[i] = xv[i];
        }
    }
    __syncthreads();
    if (gid >= B) return;

    const float* __restrict__ Zb  = ws + 1352;
    const float* __restrict__ z2s = ws + 1602;
    const float* __restrict__ ils = ws + 1652;
    const float pv = ws[1657];

    float xs[5];
    #pragma unroll
    for (int j = 0; j < 5; ++j) xs[j] = sx[t * 5 + j] * ils[j];

    float x2 = 0.0f;
    #pragma unroll
    for (int j = 0; j < 5; ++j) x2 = fmaf(xs[j], xs[j], x2);

    f32x2 kp[25];
    #pragma unroll
    for (int m = 0; m < M; ++m) {
        float u = x2 + z2s[m];
        #pragma unroll
        for (int j = 0; j < 5; ++j) u = fmaf(Zb[m * 5 + j], xs[j], u);
        u = fmaxf(u, 5e-8f);
        float s = fsqrt(u);
        float e = fexp2(s * -1.4426950408889634f);          // exp(-s)
        float kv = fmaf(u, (1.0f / 3.0f), 1.0f + s) * e;
        if (m & 1) kp[m >> 1].y = kv; else kp[m >> 1].x = kv;
    }

    float red = 0.0f;
    #pragma unroll
    for (int m = 0; m < M; ++m) {
        const int h  = m >> 1;
        const int po = PO(m);
        const int nq = NPP(m) / 2;
        f32x2 acc; acc.x = 0.0f; acc.y = 0.0f;
        #pragma unroll
        for (int q = 0; q < nq; ++q) {
            f32x4 c = *(const f32x4*)&sP[(po + 2 * q) * 2];
            const int k0 = (h + 2 * q < 25)     ? h + 2 * q     : 0;
            const int k1 = (h + 2 * q + 1 < 25) ? h + 2 * q + 1 : 0;
            pkfma(acc, c.xy, kp[k0]);
            pkfma(acc, c.zw, kp[k1]);
        }
        float tm = acc.x + acc.y;
        float km = (m & 1) ? kp[h].y : kp[h].x;
        red = fmaf(km, tm, red);
    }

    out[gid] = fsqrt(fmaxf(pv - red, 1e-6f));
}

extern "C" void kernel_launch(void* const* d_in, const int* in_sizes, int n_in,
                              void* d_out, int out_size, void* d_ws, size_t ws_size,
                              hipStream_t stream) {
    const float* x    = (const float*)d_in[0];
    const float* ll   = (const float*)d_in[1];
    const float* lv   = (const float*)d_in[2];
    const float* zraw = (const float*)d_in[3];
    float* out = (float*)d_out;
    float* ws  = (float*)d_ws;

    const int B = in_sizes[0] / 5;

    hipLaunchKernelGGL(gp_setup, dim3(1), dim3(256), 0, stream, ll, lv, zraw, ws);
    const int grid = (B + 255) / 256;
    hipLaunchKernelGGL(gp_var, dim3(grid), dim3(256), 0, stream, x, ws, out, B);
}

// Round 9
// 72.723 us; speedup vs baseline: 4.4657x; 1.2393x over previous
//
#include <hip/hip_runtime.h>
#include <hip/hip_bf16.h>
#include <math.h>

#define M 50
#define SQRT5 2.2360679774997896f

typedef short  bf16x8 __attribute__((ext_vector_type(8)));
typedef float  f32x4v __attribute__((ext_vector_type(4)));

__constant__ float c_zscale[5] = {0.25f, 0.2f, 0.08f, 400.0f, 10.0f};
__constant__ float c_zshift[5] = {0.0f, 0.0f, 0.0f, 800.0f, 12.0f};

#if __has_builtin(__builtin_amdgcn_sqrtf)
__device__ __forceinline__ float fsqrt(float x) { return __builtin_amdgcn_sqrtf(x); }
#else
__device__ __forceinline__ float fsqrt(float x) { return sqrtf(x); }
#endif

#if __has_builtin(__builtin_amdgcn_exp2f)
__device__ __forceinline__ float fexp2(float x) { return __builtin_amdgcn_exp2f(x); }
#else
__device__ __forceinline__ float fexp2(float x) { return exp2f(x); }
#endif

__device__ __forceinline__ float lane_bcast(float v, int lane) {
    return __builtin_bit_cast(float,
        __builtin_amdgcn_readlane(__builtin_bit_cast(int, v), lane));
}

__device__ __forceinline__ unsigned short bfu(float f) {
    return __builtin_bit_cast(unsigned short, __float2bfloat16(f));
}

// ---- preprocessor 0..49 repeat machinery (literal unrolling is mandatory:
//      #pragma unroll silently failed on these loops in rounds 6/7 ->
//      runtime indices -> scratch lowering) ----
#define FOR50(F) F(0) F(1) F(2) F(3) F(4) F(5) F(6) F(7) F(8) F(9) \
  F(10) F(11) F(12) F(13) F(14) F(15) F(16) F(17) F(18) F(19) \
  F(20) F(21) F(22) F(23) F(24) F(25) F(26) F(27) F(28) F(29) \
  F(30) F(31) F(32) F(33) F(34) F(35) F(36) F(37) F(38) F(39) \
  F(40) F(41) F(42) F(43) F(44) F(45) F(46) F(47) F(48) F(49)
#define FOR50P(F, p) F(0,p) F(1,p) F(2,p) F(3,p) F(4,p) F(5,p) F(6,p) F(7,p) F(8,p) F(9,p) \
  F(10,p) F(11,p) F(12,p) F(13,p) F(14,p) F(15,p) F(16,p) F(17,p) F(18,p) F(19,p) \
  F(20,p) F(21,p) F(22,p) F(23,p) F(24,p) F(25,p) F(26,p) F(27,p) F(28,p) F(29,p) \
  F(30,p) F(31,p) F(32,p) F(33,p) F(34,p) F(35,p) F(36,p) F(37,p) F(38,p) F(39,p) \
  F(40,p) F(41,p) F(42,p) F(43,p) F(44,p) F(45,p) F(46,p) F(47,p) F(48,p) F(49,p)

// Gauss-Jordan (lane j owns column j of K; in-place; s_K := K^-1)
#define DECL_R(i) float r##i;
#define INIT_R(i) r##i = s_K[(i) * M + jc];
#define UPD(i, p) if ((i) != (p)) { \
    const float cp = lane_bcast(r##i, (p)); \
    r##i = fmaf(-cp, rowv, onp ? 0.0f : r##i); }
#define PIVOT(p) { \
    const float piv  = lane_bcast(r##p, (p)); \
    const float ipv  = 1.0f / piv; \
    const bool  onp  = (j == (p)); \
    const float rowv = onp ? ipv : r##p * ipv; \
    FOR50P(UPD, p) \
    r##p = rowv; }
#define WB_R(i) s_K[(i) * M + j] = r##i;

// Cholesky of A = K^-1 (lane i owns ROW i; A symmetric so rows==cols).
// After CH_PIVOT(p): c##p on lane i holds L[i][p] (valid for i >= p).
#define DECL_C(i) float c##i;
#define INIT_C(i) c##i = s_K[lrow * M + (i)];
#define CH_UPD(i, p) if ((i) > (p)) { \
    const float cj = lane_bcast(c##p, (i)); \
    c##i = fmaf(-c##p, cj, c##i); }
#define CH_PIVOT(p) { \
    const float dp  = lane_bcast(c##p, (p)); \
    const float inv = 1.0f / fsqrt(dp); \
    c##p *= inv; \
    FOR50P(CH_UPD, p) }
// Wt[n][i] = pv * L[i][n]  (row-major [64][64] ushort at ws+512 floats)
#define WB_C(i) if (t < M && (i) <= t) wtp[(i) * 64 + t] = bfu(pv * c##i);

// ---------------------------------------------------------------------------
// ws layout (floats):
//   [0   .. 250)   Zb[m][j] = -2*sqrt5*Zs[m][j]
//   [256 .. 306)   z2s[m]   = |sqrt5*Zs[m]|^2 + 5e-8
//   [320 .. 325)   ils[j]   = sqrt5 * inv_ls[j]
//   [326]          prior_var
//   [512 .. 2560)  Wt: bf16[64][64], Wt[n][m] = pv*L[m][n], zero-padded,
//                  where A = K^-1 = L L^T  ->  red = || Wt^T-free: y=k@W ||^2
// ---------------------------------------------------------------------------
__global__ __launch_bounds__(256, 1) void gp_setup(const float* __restrict__ log_ls,
                                                   const float* __restrict__ log_var,
                                                   const float* __restrict__ zraw,
                                                   float* __restrict__ ws) {
    __shared__ float s_ils[5];
    __shared__ float s_pv;
    __shared__ float s_Zs[M * 5];
    __shared__ float s_K[M * M];

    const int t = threadIdx.x;
    unsigned short* wtp = (unsigned short*)(ws + 512);

    if (t == 0) s_pv = expf(log_var[0]);
    if (t < 5)  s_ils[t] = 1.0f / (expf(log_ls[t]) + 1e-8f);
    __syncthreads();
    if (t < M * 5) {
        int j = t % 5;
        s_Zs[t] = (tanhf(zraw[t]) * c_zscale[j] + c_zshift[j]) * s_ils[j];
    }
    __syncthreads();
    const float pv = s_pv;

    // Zero Wt region (all threads) + build K + 1e-4 I (all threads)
    for (int e = t; e < 4096; e += 256) wtp[e] = 0;
    for (int e = t; e < M * M; e += 256) {
        int i = e / M, jj = e % M;
        float d2 = 0.0f;
        #pragma unroll
        for (int q = 0; q < 5; ++q) {
            float df = s_Zs[i * 5 + q] - s_Zs[jj * 5 + q];
            d2 = fmaf(df, df, d2);
        }
        float d = fsqrt(d2 + 1e-8f);
        float s = SQRT5 * d;
        s_K[e] = pv * (1.0f + s + (5.0f / 3.0f) * (d * d)) * expf(-s)
                 + ((i == jj) ? 1e-4f : 0.0f);
    }
    __syncthreads();

    // Wave 0: GJ inverse (s_K := A = K^-1), then Cholesky A = L L^T,
    // then emit Wt = pv * L^T in bf16. All literally unrolled, zero barriers.
    if (t < 64) {
        {
            const int j  = t;
            const int jc = (j < M) ? j : (M - 1);
            FOR50(DECL_R)
            FOR50(INIT_R)
            FOR50(PIVOT)
            if (j < M) { FOR50(WB_R) }
        }
        {
            const int lrow = (t < M) ? t : (M - 1);
            FOR50(DECL_C)
            FOR50(INIT_C)
            FOR50(CH_PIVOT)
            FOR50(WB_C)
        }
    }

    // Independent emissions (all threads; disjoint regions)
    if (t < M * 5) ws[t] = -2.0f * SQRT5 * s_Zs[t];
    if (t < M) {
        float z2 = 0.0f;
        #pragma unroll
        for (int q = 0; q < 5; ++q) {
            float v = SQRT5 * s_Zs[t * 5 + q];
            z2 = fmaf(v, v, z2);
        }
        ws[256 + t] = z2 + 5e-8f;
    }
    if (t < 5)  ws[320 + t] = SQRT5 * s_ils[t];
    if (t == 0) ws[326] = pv;
}

// ---------------------------------------------------------------------------
// Main kernel. Per wave (64 points, one per lane):
//   1) generate k[50] in fp32 (as round 8)
//   2) round to bf16, pack, XOR-swizzled store into this wave's LDS k-matrix
//      [64 pts][64 kdims] (kdims 50..63 zero)
//   3) y(64x64) = k @ W via 32x mfma_f32_16x16x32_bf16 (fp32 accumulate)
//   4) red[pt] = sum_n y^2 : square C/D frags, butterfly over 16-lane groups
//   5) out = sqrt(max(pv - red, 1e-6))
// A-frag: lane holds A[l&15][(l>>4)*8+e]; B-frag: B[(l>>4)*8+e][l&15]
// (contiguous 16B reads from swizzled LDS / row-major Wt).
// C/D: col=lane&15, row=(lane>>4)*4+reg  [verified layout].
// ---------------------------------------------------------------------------
__global__ __launch_bounds__(256) void gp_var(const float* __restrict__ x,
                                              const float* __restrict__ ws,
                                              float* __restrict__ out, int B) {
    __shared__ float sx[1280];
    __shared__ __align__(16) unsigned short sk[4 * 64 * 64];   // 32 KB
    const int t    = threadIdx.x;
    const int lane = t & 63;
    const int wid  = t >> 6;
    const long long base = (long long)blockIdx.x * 1280;

    {
        const long long tot = (long long)B * 5;
        const float4* xv = (const float4*)(x + base);
        for (int i = t; i < 320; i += 256) {
            if (base + (long long)i * 4 + 3 < tot) ((float4*)sx)[i] = xv[i];
        }
    }
    __syncthreads();

    const float* __restrict__ Zb  = ws;
    const float* __restrict__ z2s = ws + 256;
    const float* __restrict__ ils = ws + 320;
    const float pv = ws[326];

    float xs[5];
    #pragma unroll
    for (int j = 0; j < 5; ++j) xs[j] = sx[t * 5 + j] * ils[j];

    float x2 = 0.0f;
    #pragma unroll
    for (int j = 0; j < 5; ++j) x2 = fmaf(xs[j], xs[j], x2);

    float k[M];
    #pragma unroll
    for (int m = 0; m < M; ++m) {
        float u = x2 + z2s[m];
        #pragma unroll
        for (int j = 0; j < 5; ++j) u = fmaf(Zb[m * 5 + j], xs[j], u);
        u = fmaxf(u, 5e-8f);
        float s = fsqrt(u);
        float e = fexp2(s * -1.4426950408889634f);          // exp(-s)
        k[m] = fmaf(u, (1.0f / 3.0f), 1.0f + s) * e;
    }

    // 2) bf16-pack + swizzled LDS write of this lane's k-row (128 B)
    char* kbase = (char*)sk + wid * 8192;
    const int swz_w = (lane & 7) << 4;
    #pragma unroll
    for (int c = 0; c < 8; ++c) {
        unsigned int w0, w1, w2, w3;
        #pragma unroll
        for (int q = 0; q < 4; ++q) {
            int kd0 = c * 8 + q * 2, kd1 = kd0 + 1;
            float f0 = (kd0 < M) ? k[kd0] : 0.0f;
            float f1 = (kd1 < M) ? k[kd1] : 0.0f;
            unsigned int wv = (unsigned int)bfu(f0) | ((unsigned int)bfu(f1) << 16);
            if (q == 0) w0 = wv; else if (q == 1) w1 = wv;
            else if (q == 2) w2 = wv; else w3 = wv;
        }
        int off = lane * 128 + ((c * 16) ^ swz_w);
        *(int4*)(kbase + off) = make_int4((int)w0, (int)w1, (int)w2, (int)w3);
    }

    // 3) W fragments from global (L2-resident, once per thread)
    const int r15 = lane & 15, g = lane >> 4;
    bf16x8 wf[4][2];
    const char* wtb = (const char*)(ws + 512);
    #pragma unroll
    for (int tc = 0; tc < 4; ++tc) {
        #pragma unroll
        for (int ks = 0; ks < 2; ++ks) {
            int o = ((tc * 16 + r15) * 64 + ks * 32 + g * 8) * 2;
            wf[tc][ks] = *(const bf16x8*)(wtb + o);
        }
    }

    // 3b) MFMA: per row-tile, read A-frags and accumulate squares per reg
    float part[4][4];
    #pragma unroll
    for (int tr = 0; tr < 4; ++tr) {
        const int r = tr * 16 + r15;
        const char* arow = kbase + r * 128;
        const int swz = (r15 & 7) << 4;                 // r&7 == r15&7
        bf16x8 a0 = *(const bf16x8*)(arow + ((g * 16) ^ swz));
        bf16x8 a1 = *(const bf16x8*)(arow + (((4 + g) * 16) ^ swz));
        #pragma unroll
        for (int tc = 0; tc < 4; ++tc) {
            f32x4v acc = {0.0f, 0.0f, 0.0f, 0.0f};
            acc = __builtin_amdgcn_mfma_f32_16x16x32_bf16(a0, wf[tc][0], acc, 0, 0, 0);
            acc = __builtin_amdgcn_mfma_f32_16x16x32_bf16(a1, wf[tc][1], acc, 0, 0, 0);
            #pragma unroll
            for (int rg = 0; rg < 4; ++rg) {
                part[tr][rg] = (tc == 0) ? acc[rg] * acc[rg]
                                         : fmaf(acc[rg], acc[rg], part[tr][rg]);
            }
        }
    }

    // 4) butterfly-sum over the 16 lanes of each l>>4 group
    #pragma unroll
    for (int tr = 0; tr < 4; ++tr) {
        #pragma unroll
        for (int rg = 0; rg < 4; ++rg) {
            float v = part[tr][rg];
            v += __shfl_xor(v, 1);
            v += __shfl_xor(v, 2);
            v += __shfl_xor(v, 4);
            v += __shfl_xor(v, 8);
            part[tr][rg] = v;
        }
    }

    // 5) lane (l&15)=c writes point (c>>2)*16 + g*4 + (c&3) of this wave
    float red = part[0][0];
    #pragma unroll
    for (int i = 1; i < 16; ++i)
        if (r15 == i) red = part[i >> 2][i & 3];

    const int pt = blockIdx.x * 256 + wid * 64 + (r15 >> 2) * 16 + g * 4 + (r15 & 3);
    out[pt] = fsqrt(fmaxf(pv - red, 1e-6f));
}

extern "C" void kernel_launch(void* const* d_in, const int* in_sizes, int n_in,
                              void* d_out, int out_size, void* d_ws, size_t ws_size,
                              hipStream_t stream) {
    const float* x    = (const float*)d_in[0];
    const float* ll   = (const float*)d_in[1];
    const float* lv   = (const float*)d_in[2];
    const float* zraw = (const float*)d_in[3];
    float* out = (float*)d_out;
    float* ws  = (float*)d_ws;

    const int B = in_sizes[0] / 5;

    hipLaunchKernelGGL(gp_setup, dim3(1), dim3(256), 0, stream, ll, lv, zraw, ws);
    const int grid = (B + 255) / 256;
    hipLaunchKernelGGL(gp_var, dim3(grid), dim3(256), 0, stream, x, ws, out, B);
}

// Round 10
// 60.077 us; speedup vs baseline: 5.4057x; 1.2105x over previous
//
#include <hip/hip_runtime.h>
#include <hip/hip_bf16.h>
#include <math.h>

#define M 50
#define SQRT5 2.2360679774997896f

typedef short  bf16x8 __attribute__((ext_vector_type(8)));
typedef float  f32x4v __attribute__((ext_vector_type(4)));

__constant__ float c_zscale[5] = {0.25f, 0.2f, 0.08f, 400.0f, 10.0f};
__constant__ float c_zshift[5] = {0.0f, 0.0f, 0.0f, 800.0f, 12.0f};

#if __has_builtin(__builtin_amdgcn_sqrtf)
__device__ __forceinline__ float fsqrt(float x) { return __builtin_amdgcn_sqrtf(x); }
#else
__device__ __forceinline__ float fsqrt(float x) { return sqrtf(x); }
#endif

#if __has_builtin(__builtin_amdgcn_exp2f)
__device__ __forceinline__ float fexp2(float x) { return __builtin_amdgcn_exp2f(x); }
#else
__device__ __forceinline__ float fexp2(float x) { return exp2f(x); }
#endif

#if __has_builtin(__builtin_amdgcn_rcpf)
__device__ __forceinline__ float frcp(float x) { return __builtin_amdgcn_rcpf(x); }
#else
__device__ __forceinline__ float frcp(float x) { return 1.0f / x; }
#endif

__device__ __forceinline__ float lane_bcast(float v, int lane) {
    return __builtin_bit_cast(float,
        __builtin_amdgcn_readlane(__builtin_bit_cast(int, v), lane));
}

__device__ __forceinline__ unsigned short bfu(float f) {
    return __builtin_bit_cast(unsigned short, __float2bfloat16(f));
}

// ---- preprocessor 0..49 repeat machinery (literal unrolling is mandatory:
//      #pragma unroll silently failed on 50-deep pivot loops in rounds 6/7 ->
//      runtime indices -> scratch lowering) ----
#define FOR50(F) F(0) F(1) F(2) F(3) F(4) F(5) F(6) F(7) F(8) F(9) \
  F(10) F(11) F(12) F(13) F(14) F(15) F(16) F(17) F(18) F(19) \
  F(20) F(21) F(22) F(23) F(24) F(25) F(26) F(27) F(28) F(29) \
  F(30) F(31) F(32) F(33) F(34) F(35) F(36) F(37) F(38) F(39) \
  F(40) F(41) F(42) F(43) F(44) F(45) F(46) F(47) F(48) F(49)
#define FOR50P(F, p) F(0,p) F(1,p) F(2,p) F(3,p) F(4,p) F(5,p) F(6,p) F(7,p) F(8,p) F(9,p) \
  F(10,p) F(11,p) F(12,p) F(13,p) F(14,p) F(15,p) F(16,p) F(17,p) F(18,p) F(19,p) \
  F(20,p) F(21,p) F(22,p) F(23,p) F(24,p) F(25,p) F(26,p) F(27,p) F(28,p) F(29,p) \
  F(30,p) F(31,p) F(32,p) F(33,p) F(34,p) F(35,p) F(36,p) F(37,p) F(38,p) F(39,p) \
  F(40,p) F(41,p) F(42,p) F(43,p) F(44,p) F(45,p) F(46,p) F(47,p) F(48,p) F(49,p)

// ---- Phase A: Cholesky of K' = K + 1e-4 I (lane i owns ROW i in registers)
// After CH_PIVOT(p): c##p on lane i == L[i][p]; flushed to LDS (s_K reused
// as L storage, row-major [i][p]) and dead -> live set tapers 50 -> 0.
#define DECL_C(i) float c##i;
#define INIT_C(i) c##i = s_K[lrow * M + (i)];
#define CH_UPD(i, p) if ((i) > (p)) { \
    const float cj = lane_bcast(c##p, (i)); \
    c##i = fmaf(-c##p, cj, c##i); }
#define CH_PIVOT(p) { \
    const float dp  = lane_bcast(c##p, (p)); \
    const float inv = frcp(fsqrt(dp)); \
    c##p *= inv; \
    if (lane < M) s_K[lane * M + (p)] = c##p; \
    FOR50P(CH_UPD, p) }

// ---- Phase B: lane j solves L y = e_j (forward substitution). Lane-local,
// no cross-lane ops; L read from LDS at static uniform addresses (broadcast).
// y##i = Linv[i][j].
#define DECL_Y(i) float y##i;
#define TSU(q, i) if ((q) < (i)) acc = fmaf(-s_K[(i) * M + (q)], y##q, acc);
#define TS_ROW(i) { \
    float acc = (lane == (i)) ? 1.0f : 0.0f; \
    FOR50P(TSU, i) \
    y##i = acc * frcp(s_K[(i) * M + (i)]); }

// ---- Emission: Wt[n][lane] = bf16(pv * Linv[n][lane]), row-major [64][64].
// red = ||y||^2 = pv^2 k^T K'^-1 k  (same storage layout as round 9 ->
// gp_var unchanged).
#define W_EMIT(i) wtp[(i) * 64 + lane] = bfu(pv * y##i);

// ---------------------------------------------------------------------------
// ws layout (floats):
//   [0   .. 250)   Zb[m][j] = -2*sqrt5*Zs[m][j]
//   [256 .. 306)   z2s[m]   = |sqrt5*Zs[m]|^2 + 5e-8
//   [320 .. 325)   ils[j]   = sqrt5 * inv_ls[j]
//   [326]          prior_var
//   [512 .. 2560)  Wt: bf16[64][64], Wt[n][m] = pv*Linv[n][m], zero-padded
// ---------------------------------------------------------------------------
__global__ __launch_bounds__(256, 1) void gp_setup(const float* __restrict__ log_ls,
                                                   const float* __restrict__ log_var,
                                                   const float* __restrict__ zraw,
                                                   float* __restrict__ ws) {
    __shared__ float s_ils[5];
    __shared__ float s_pv;
    __shared__ float s_Zs[M * 5];
    __shared__ float s_K[M * M];

    const int t = threadIdx.x;
    unsigned short* wtp = (unsigned short*)(ws + 512);

    if (t == 0) s_pv = expf(log_var[0]);
    if (t < 5)  s_ils[t] = 1.0f / (expf(log_ls[t]) + 1e-8f);
    __syncthreads();
    if (t < M * 5) {
        int j = t % 5;
        s_Zs[t] = (tanhf(zraw[t]) * c_zscale[j] + c_zshift[j]) * s_ils[j];
    }
    __syncthreads();
    const float pv = s_pv;

    // Zero Wt region + build K + 1e-4 I (parallel across 256 threads)
    for (int e = t; e < 4096; e += 256) wtp[e] = 0;
    for (int e = t; e < M * M; e += 256) {
        int i = e / M, jj = e % M;
        float d2 = 0.0f;
        #pragma unroll
        for (int q = 0; q < 5; ++q) {
            float df = s_Zs[i * 5 + q] - s_Zs[jj * 5 + q];
            d2 = fmaf(df, df, d2);
        }
        float d = fsqrt(d2 + 1e-8f);
        float s = SQRT5 * d;
        s_K[e] = pv * (1.0f + s + (5.0f / 3.0f) * (d * d)) * expf(-s)
                 + ((i == jj) ? 1e-4f : 0.0f);
    }
    __syncthreads();

    // Wave 0: Cholesky K' = L L^T (registers, flush L to s_K), then
    // lane-local trisolve Linv columns, then bf16 Wt emission.
    if (t < 64) {
        const int lane = t;
        const int lrow = (t < M) ? t : (M - 1);
        {
            FOR50(DECL_C)
            FOR50(INIT_C)
            FOR50(CH_PIVOT)
        }
        {
            FOR50(DECL_Y)
            FOR50(TS_ROW)
            FOR50(W_EMIT)
        }
    }

    // Independent emissions (all threads; disjoint regions)
    if (t < M * 5) ws[t] = -2.0f * SQRT5 * s_Zs[t];
    if (t < M) {
        float z2 = 0.0f;
        #pragma unroll
        for (int q = 0; q < 5; ++q) {
            float v = SQRT5 * s_Zs[t * 5 + q];
            z2 = fmaf(v, v, z2);
        }
        ws[256 + t] = z2 + 5e-8f;
    }
    if (t < 5)  ws[320 + t] = SQRT5 * s_ils[t];
    if (t == 0) ws[326] = pv;
}

// ---------------------------------------------------------------------------
// Main kernel (byte-identical to round 9). Per wave (64 points, 1/lane):
// k-gen fp32 -> bf16 swizzled LDS -> 32x mfma_f32_16x16x32_bf16 -> square
// C/D frags -> 16-lane butterfly -> out = sqrt(max(pv - red, 1e-6)).
// ---------------------------------------------------------------------------
__global__ __launch_bounds__(256) void gp_var(const float* __restrict__ x,
                                              const float* __restrict__ ws,
                                              float* __restrict__ out, int B) {
    __shared__ float sx[1280];
    __shared__ __align__(16) unsigned short sk[4 * 64 * 64];   // 32 KB
    const int t    = threadIdx.x;
    const int lane = t & 63;
    const int wid  = t >> 6;
    const long long base = (long long)blockIdx.x * 1280;

    {
        const long long tot = (long long)B * 5;
        const float4* xv = (const float4*)(x + base);
        for (int i = t; i < 320; i += 256) {
            if (base + (long long)i * 4 + 3 < tot) ((float4*)sx)[i] = xv[i];
        }
    }
    __syncthreads();

    const float* __restrict__ Zb  = ws;
    const float* __restrict__ z2s = ws + 256;
    const float* __restrict__ ils = ws + 320;
    const float pv = ws[326];

    float xs[5];
    #pragma unroll
    for (int j = 0; j < 5; ++j) xs[j] = sx[t * 5 + j] * ils[j];

    float x2 = 0.0f;
    #pragma unroll
    for (int j = 0; j < 5; ++j) x2 = fmaf(xs[j], xs[j], x2);

    float k[M];
    #pragma unroll
    for (int m = 0; m < M; ++m) {
        float u = x2 + z2s[m];
        #pragma unroll
        for (int j = 0; j < 5; ++j) u = fmaf(Zb[m * 5 + j], xs[j], u);
        u = fmaxf(u, 5e-8f);
        float s = fsqrt(u);
        float e = fexp2(s * -1.4426950408889634f);          // exp(-s)
        k[m] = fmaf(u, (1.0f / 3.0f), 1.0f + s) * e;
    }

    // bf16-pack + swizzled LDS write of this lane's k-row (128 B)
    char* kbase = (char*)sk + wid * 8192;
    const int swz_w = (lane & 7) << 4;
    #pragma unroll
    for (int c = 0; c < 8; ++c) {
        unsigned int w0, w1, w2, w3;
        #pragma unroll
        for (int q = 0; q < 4; ++q) {
            int kd0 = c * 8 + q * 2, kd1 = kd0 + 1;
            float f0 = (kd0 < M) ? k[kd0] : 0.0f;
            float f1 = (kd1 < M) ? k[kd1] : 0.0f;
            unsigned int wv = (unsigned int)bfu(f0) | ((unsigned int)bfu(f1) << 16);
            if (q == 0) w0 = wv; else if (q == 1) w1 = wv;
            else if (q == 2) w2 = wv; else w3 = wv;
        }
        int off = lane * 128 + ((c * 16) ^ swz_w);
        *(int4*)(kbase + off) = make_int4((int)w0, (int)w1, (int)w2, (int)w3);
    }

    // W fragments from global (L2-resident)
    const int r15 = lane & 15, g = lane >> 4;
    bf16x8 wf[4][2];
    const char* wtb = (const char*)(ws + 512);
    #pragma unroll
    for (int tc = 0; tc < 4; ++tc) {
        #pragma unroll
        for (int ks = 0; ks < 2; ++ks) {
            int o = ((tc * 16 + r15) * 64 + ks * 32 + g * 8) * 2;
            wf[tc][ks] = *(const bf16x8*)(wtb + o);
        }
    }

    // MFMA + per-reg square accumulation
    float part[4][4];
    #pragma unroll
    for (int tr = 0; tr < 4; ++tr) {
        const int r = tr * 16 + r15;
        const char* arow = kbase + r * 128;
        const int swz = (r15 & 7) << 4;
        bf16x8 a0 = *(const bf16x8*)(arow + ((g * 16) ^ swz));
        bf16x8 a1 = *(const bf16x8*)(arow + (((4 + g) * 16) ^ swz));
        #pragma unroll
        for (int tc = 0; tc < 4; ++tc) {
            f32x4v acc = {0.0f, 0.0f, 0.0f, 0.0f};
            acc = __builtin_amdgcn_mfma_f32_16x16x32_bf16(a0, wf[tc][0], acc, 0, 0, 0);
            acc = __builtin_amdgcn_mfma_f32_16x16x32_bf16(a1, wf[tc][1], acc, 0, 0, 0);
            #pragma unroll
            for (int rg = 0; rg < 4; ++rg) {
                part[tr][rg] = (tc == 0) ? acc[rg] * acc[rg]
                                         : fmaf(acc[rg], acc[rg], part[tr][rg]);
            }
        }
    }

    // butterfly-sum over the 16 lanes of each l>>4 group
    #pragma unroll
    for (int tr = 0; tr < 4; ++tr) {
        #pragma unroll
        for (int rg = 0; rg < 4; ++rg) {
            float v = part[tr][rg];
            v += __shfl_xor(v, 1);
            v += __shfl_xor(v, 2);
            v += __shfl_xor(v, 4);
            v += __shfl_xor(v, 8);
            part[tr][rg] = v;
        }
    }

    float red = part[0][0];
    #pragma unroll
    for (int i = 1; i < 16; ++i)
        if (r15 == i) red = part[i >> 2][i & 3];

    const int pt = blockIdx.x * 256 + wid * 64 + (r15 >> 2) * 16 + g * 4 + (r15 & 3);
    out[pt] = fsqrt(fmaxf(pv - red, 1e-6f));
}

extern "C" void kernel_launch(void* const* d_in, const int* in_sizes, int n_in,
                              void* d_out, int out_size, void* d_ws, size_t ws_size,
                              hipStream_t stream) {
    const float* x    = (const float*)d_in[0];
    const float* ll   = (const float*)d_in[1];
    const float* lv   = (const float*)d_in[2];
    const float* zraw = (const float*)d_in[3];
    float* out = (float*)d_out;
    float* ws  = (float*)d_ws;

    const int B = in_sizes[0] / 5;

    hipLaunchKernelGGL(gp_setup, dim3(1), dim3(256), 0, stream, ll, lv, zraw, ws);
    const int grid = (B + 255) / 256;
    hipLaunchKernelGGL(gp_var, dim3(grid), dim3(256), 0, stream, x, ws, out, B);
}